// Round 3
// baseline (388.256 us; speedup 1.0000x reference)
//
#include <hip/hip_runtime.h>
#include <hip/hip_bf16.h>
#include <stdint.h>

typedef __hip_bfloat16 bf16;
typedef __bf16 bf16x8 __attribute__((ext_vector_type(8)));
typedef float f32x4 __attribute__((ext_vector_type(4)));

#define MFMA16(a, b, c) __builtin_amdgcn_mfma_f32_16x16x32_bf16((a), (b), (c), 0, 0, 0)

__device__ __forceinline__ void gload_lds16(const void* g, void* l) {
    __builtin_amdgcn_global_load_lds((const __attribute__((address_space(1))) void*)g,
                                     (__attribute__((address_space(3))) void*)l, 16, 0, 0);
}

// ---------------------------------------------------------------- cast kernel
struct alignas(16) B8 { bf16 v[8]; };
struct alignas(8)  B4 { bf16 v[4]; };

__global__ __launch_bounds__(256) void cast_all_k(
    const float* __restrict__ x, const float* __restrict__ wqkv, const float* __restrict__ wout,
    bf16* __restrict__ xb, bf16* __restrict__ wqkvb, bf16* __restrict__ woutb) {
    const size_t NX = (size_t)2048 * 2048 / 8;
    const size_t NW = (size_t)3 * 2048 * 2048 / 8;
    size_t i = (size_t)blockIdx.x * 256 + threadIdx.x;
    const float* s; bf16* d;
    if (i < NX)            { s = x;    d = xb; }
    else if (i < NX + NW)  { s = wqkv; d = wqkvb; i -= NX; }
    else                   { s = wout; d = woutb; i -= NX + NW; }
    float4 a = ((const float4*)s)[2 * i];
    float4 b = ((const float4*)s)[2 * i + 1];
    B8 t;
    t.v[0] = __float2bfloat16(a.x); t.v[1] = __float2bfloat16(a.y);
    t.v[2] = __float2bfloat16(a.z); t.v[3] = __float2bfloat16(a.w);
    t.v[4] = __float2bfloat16(b.x); t.v[5] = __float2bfloat16(b.y);
    t.v[6] = __float2bfloat16(b.z); t.v[7] = __float2bfloat16(b.w);
    ((B8*)d)[i] = t;
}

// ---------------------------------------------------------------- GEMM (B^T)
__global__ __launch_bounds__(256) void gemm_bt(
    const bf16* __restrict__ A, const bf16* __restrict__ B, float* __restrict__ C,
    int M, int N, int K) {
    __shared__ __align__(16) bf16 As[128 * 32];
    __shared__ __align__(16) bf16 Bs[128 * 32];
    const int t = threadIdx.x;
    const int lane = t & 63, w = t >> 6;
    const int wr = w >> 1, wc = w & 1;
    const int l15 = lane & 15, lg = lane >> 4;
    const int m0 = blockIdx.y * 128, n0 = blockIdx.x * 128;

    f32x4 acc[4][4] = {};

    for (int k0 = 0; k0 < K; k0 += 32) {
#pragma unroll
        for (int c = 0; c < 2; ++c) {
            int f = t + c * 256;
            int row = f >> 2, cb = f & 3;
            gload_lds16(&A[(size_t)(m0 + row) * K + k0 + cb * 8], &As[f * 8]);
            gload_lds16(&B[(size_t)(n0 + row) * K + k0 + cb * 8], &Bs[f * 8]);
        }
        __syncthreads();

        bf16x8 af[4], bfr[4];
#pragma unroll
        for (int mi = 0; mi < 4; ++mi)
            af[mi] = *(const bf16x8*)&As[(wr * 64 + mi * 16 + l15) * 32 + lg * 8];
#pragma unroll
        for (int ni = 0; ni < 4; ++ni)
            bfr[ni] = *(const bf16x8*)&Bs[(wc * 64 + ni * 16 + l15) * 32 + lg * 8];
#pragma unroll
        for (int mi = 0; mi < 4; ++mi)
#pragma unroll
            for (int ni = 0; ni < 4; ++ni)
                acc[mi][ni] = MFMA16(af[mi], bfr[ni], acc[mi][ni]);
        __syncthreads();
    }

#pragma unroll
    for (int mi = 0; mi < 4; ++mi) {
        int r0 = m0 + wr * 64 + mi * 16 + lg * 4;
#pragma unroll
        for (int ni = 0; ni < 4; ++ni) {
            int c0 = n0 + wc * 64 + ni * 16 + l15;
#pragma unroll
            for (int j = 0; j < 4; ++j)
                C[(size_t)(r0 + j) * N + c0] = acc[mi][ni][j];
        }
    }
}

// ---------------------------------------------------------------- RMSNorm+RoPE
// One block (128 thr) per (t, h). Writes qb/kb bf16 in [H][T][128].
__global__ __launch_bounds__(128) void normrope_k(
    const float* __restrict__ qkv, bf16* __restrict__ qb, bf16* __restrict__ kb) {
    const int t = blockIdx.x, h = blockIdx.y, d = threadIdx.x;
    const float* base = qkv + (size_t)t * 6144;
    float q = base[h * 128 + d];
    float k = base[2048 + h * 128 + d];

    __shared__ float red[4];
    __shared__ float qn[128], kn[128];
    float sq = q * q, sk = k * k;
#pragma unroll
    for (int m = 1; m <= 32; m <<= 1) {
        sq += __shfl_xor(sq, m);
        sk += __shfl_xor(sk, m);
    }
    if ((d & 63) == 0) { red[(d >> 6) * 2] = sq; red[(d >> 6) * 2 + 1] = sk; }
    __syncthreads();
    float rq = rsqrtf((red[0] + red[2]) * (1.0f / 128.0f) + 1e-6f);
    float rk = rsqrtf((red[1] + red[3]) * (1.0f / 128.0f) + 1e-6f);
    qn[d] = q * rq;
    kn[d] = k * rk;
    __syncthreads();

    int j = d & 63;
    float c = 1.0f, s = 0.0f;
    if (j < 32) {
        float af = exp2f(-10.0f * (float)j / 31.0f);
        float theta = (float)t * af;
        sincosf(theta, &s, &c);
    }
    float oq, ok;
    if (d < 64) { oq =  qn[d] * c + qn[d + 64] * s;  ok =  kn[d] * c + kn[d + 64] * s; }
    else        { oq = -qn[d - 64] * s + qn[d] * c;  ok = -kn[d - 64] * s + kn[d] * c; }

    size_t oidx = ((size_t)h * 2048 + t) * 128 + d;
    qb[oidx] = __float2bfloat16(oq * 0.08838834764831845f);
    kb[oidx] = __float2bfloat16(ok);
}

// ---------------------------------------------------------------- V transpose
// vt[h][d][t] bf16 from qkvf fp32 v-part. Tile 64t x 64d per block.
__global__ __launch_bounds__(256) void vtrans_k(
    const float* __restrict__ qkv, bf16* __restrict__ vt) {
    __shared__ bf16 Ts[64][72];
    const int t0 = blockIdx.x * 64, d0 = blockIdx.y * 64, h = blockIdx.z;
    const int tid = threadIdx.x;
#pragma unroll
    for (int it = 0; it < 4; ++it) {
        int f = tid + it * 256;            // 0..1023 float4 slots
        int tl = f >> 4, dl = (f & 15) * 4;
        float4 v = *(const float4*)&qkv[(size_t)(t0 + tl) * 6144 + 4096 + h * 128 + d0 + dl];
        Ts[tl][dl + 0] = __float2bfloat16(v.x);
        Ts[tl][dl + 1] = __float2bfloat16(v.y);
        Ts[tl][dl + 2] = __float2bfloat16(v.z);
        Ts[tl][dl + 3] = __float2bfloat16(v.w);
    }
    __syncthreads();
#pragma unroll
    for (int it = 0; it < 2; ++it) {
        int f = tid + it * 256;            // 0..511 8-elem slots
        int dl = f >> 3, tc = f & 7;
        B8 p;
#pragma unroll
        for (int i = 0; i < 8; ++i) p.v[i] = Ts[tc * 8 + i][dl];
        *(B8*)&vt[((size_t)h * 128 + d0 + dl) * 2048 + t0 + tc * 8] = p;
    }
}

// ---------------------------------------------------------------- attention (split-KV)
// Grid (cz=4, qt=32, h=16). Block: 4 waves, QBLK=64 rows (16/wave), KVBLK=64.
// Chunk cz covers keys [cz*512, min((cz+1)*512, (qt+1)*64)); inactive if cz > qt>>3.
// Writes partial (m[64], l[64], O[64][128]) fp32 per chunk into `part`.
__global__ __launch_bounds__(256) void attn_main_k(
    const bf16* __restrict__ qg, const bf16* __restrict__ kg,
    const bf16* __restrict__ vt, float* __restrict__ part) {
    const int T = 2048, D = 128;
    const int cz = blockIdx.x, qt = blockIdx.y, h = blockIdx.z;
    if (cz > (qt >> 3)) return;
    const int qb0 = qt * 64;
    const int kstart = cz * 512;
    const int kend = min(kstart + 512, (qt + 1) * 64);

    __shared__ __align__(16) bf16 Ks[64 * 128];   // [key][d], 16B-chunk XOR swizzle
    __shared__ __align__(16) bf16 Vt[128 * 64];   // [d][key], 16B-chunk XOR swizzle
    __shared__ __align__(16) bf16 Ps[4][16 * 64]; // per-wave P, swizzled

    const int t = threadIdx.x;
    const int lane = t & 63, w = t >> 6;
    const int l15 = lane & 15, lg = lane >> 4;

    const size_t qoff = ((size_t)h * T + qb0 + w * 16 + l15) * D;
    bf16x8 qf[4];
#pragma unroll
    for (int ks = 0; ks < 4; ++ks)
        qf[ks] = *(const bf16x8*)&qg[qoff + ks * 32 + lg * 8];

    f32x4 o[8] = {};
    float mrow[4] = {-1e30f, -1e30f, -1e30f, -1e30f};
    float lrow[4] = {0.f, 0.f, 0.f, 0.f};

    for (int k0 = kstart; k0 < kend; k0 += 64) {
        // --- stage K [64 keys][128 d] and V^T [128 d][64 keys]
#pragma unroll
        for (int c = 0; c < 4; ++c) {
            int f = t + c * 256;                 // 0..1023 16B slots
            int krow = f >> 4, kc = f & 15;      // K: 16 chunks/row
            gload_lds16(&kg[((size_t)h * T + k0 + krow) * D + ((kc ^ (krow & 15)) * 8)],
                        &Ks[f * 8]);
            int dr = f >> 3, vc = f & 7;         // V^T: 8 chunks/row
            gload_lds16(&vt[((size_t)h * D + dr) * T + k0 + ((vc ^ (dr & 7)) * 8)],
                        &Vt[f * 8]);
        }
        __syncthreads();

        // --- S = Q K^T (scale folded into Q)
        f32x4 sc[4] = {};
#pragma unroll
        for (int ks = 0; ks < 4; ++ks) {
#pragma unroll
            for (int nb = 0; nb < 4; ++nb) {
                int key = nb * 16 + l15;
                int c = ks * 4 + lg;
                bf16x8 kf = *(const bf16x8*)&Ks[key * 128 + ((c ^ (key & 15)) * 8)];
                sc[nb] = MFMA16(qf[ks], kf, sc[nb]);
            }
        }

        const bool diag = (k0 == qb0);
        const int qrow_base = qb0 + w * 16 + lg * 4;
#pragma unroll
        for (int j = 0; j < 4; ++j) {
            float s0 = sc[0][j], s1 = sc[1][j], s2 = sc[2][j], s3 = sc[3][j];
            if (diag) {
                int qrow = qrow_base + j;
                if (k0 + l15 > qrow)      s0 = -1e30f;
                if (k0 + 16 + l15 > qrow) s1 = -1e30f;
                if (k0 + 32 + l15 > qrow) s2 = -1e30f;
                if (k0 + 48 + l15 > qrow) s3 = -1e30f;
            }
            float tm = fmaxf(fmaxf(s0, s1), fmaxf(s2, s3));
            tm = fmaxf(tm, __shfl_xor(tm, 1));
            tm = fmaxf(tm, __shfl_xor(tm, 2));
            tm = fmaxf(tm, __shfl_xor(tm, 4));
            tm = fmaxf(tm, __shfl_xor(tm, 8));
            float mnew = fmaxf(mrow[j], tm);
            float fac = __expf(mrow[j] - mnew);
            float p0 = __expf(s0 - mnew), p1 = __expf(s1 - mnew);
            float p2 = __expf(s2 - mnew), p3 = __expf(s3 - mnew);
            float ps = (p0 + p1) + (p2 + p3);
            ps += __shfl_xor(ps, 1);
            ps += __shfl_xor(ps, 2);
            ps += __shfl_xor(ps, 4);
            ps += __shfl_xor(ps, 8);
            lrow[j] = lrow[j] * fac + ps;
            mrow[j] = mnew;
#pragma unroll
            for (int nd = 0; nd < 8; ++nd) o[nd][j] *= fac;
            // write P, swizzled (chunk c = 2*nb + l15>>3, phys = c ^ (prow&7))
            int prow = lg * 4 + j;
            int sub = l15 & 7, hi = l15 >> 3;
            bf16* pw = &Ps[w][prow * 64 + sub];
            pw[(((0 + hi) ^ (prow & 7)) * 8)] = __float2bfloat16(p0);
            pw[(((2 + hi) ^ (prow & 7)) * 8)] = __float2bfloat16(p1);
            pw[(((4 + hi) ^ (prow & 7)) * 8)] = __float2bfloat16(p2);
            pw[(((6 + hi) ^ (prow & 7)) * 8)] = __float2bfloat16(p3);
        }

        // --- O += P V  (A = P rows=qrow(l15), B = V^T rows=d)
#pragma unroll
        for (int hk = 0; hk < 2; ++hk) {
            bf16x8 pf = *(const bf16x8*)&Ps[w][l15 * 64 + (((hk * 4 + lg) ^ (l15 & 7)) * 8)];
#pragma unroll
            for (int nd = 0; nd < 8; ++nd) {
                int dd = nd * 16 + l15;
                bf16x8 vf = *(const bf16x8*)&Vt[dd * 64 + (((hk * 4 + lg) ^ (dd & 7)) * 8)];
                o[nd] = MFMA16(pf, vf, o[nd]);
            }
        }
        __syncthreads();
    }

    // --- write partial record
    int b = qt >> 3, rr = qt & 7;
    int slot = h * 80 + qt + 4 * b * (b - 1) + rr * b + cz;
    float* rec = part + (size_t)slot * 8320;
    if (l15 == 0) {
#pragma unroll
        for (int j = 0; j < 4; ++j) {
            rec[w * 16 + lg * 4 + j] = mrow[j];
            rec[64 + w * 16 + lg * 4 + j] = lrow[j];
        }
    }
#pragma unroll
    for (int nd = 0; nd < 8; ++nd)
#pragma unroll
        for (int j = 0; j < 4; ++j)
            rec[128 + (w * 16 + lg * 4 + j) * 128 + nd * 16 + l15] = o[nd][j];
}

// ---------------------------------------------------------------- merge
// Grid (qt=32, h=16), 256 thr. Thread: row r = tid>>2, d-range (tid&3)*32.
__global__ __launch_bounds__(256) void attn_merge_k(
    const float* __restrict__ part, bf16* __restrict__ y) {
    const int qt = blockIdx.x, h = blockIdx.y, tid = threadIdx.x;
    const int nch = (qt >> 3) + 1;
    int b = qt >> 3, rr = qt & 7;
    const int base = h * 80 + qt + 4 * b * (b - 1) + rr * b;
    const int r = tid >> 2;
    const int d0 = (tid & 3) * 32;

    float mi[4], li[4], wgt[4];
    float M = -1e30f;
#pragma unroll
    for (int i = 0; i < 4; ++i) {
        if (i < nch) {
            mi[i] = part[(size_t)(base + i) * 8320 + r];
            li[i] = part[(size_t)(base + i) * 8320 + 64 + r];
            M = fmaxf(M, mi[i]);
        } else { mi[i] = -1e30f; li[i] = 0.f; }
    }
    float L = 0.f;
#pragma unroll
    for (int i = 0; i < 4; ++i) {
        wgt[i] = (i < nch) ? __expf(mi[i] - M) : 0.f;
        L += li[i] * wgt[i];
    }
    float invL = 1.0f / L;

    bf16* yrow = &y[(size_t)(qt * 64 + r) * 2048 + h * 128 + d0];
#pragma unroll
    for (int dd = 0; dd < 32; dd += 4) {
        float a0 = 0.f, a1 = 0.f, a2 = 0.f, a3 = 0.f;
#pragma unroll
        for (int i = 0; i < 4; ++i) {
            if (i < nch) {
                const float4 ov = *(const float4*)&part[(size_t)(base + i) * 8320 + 128 + r * 128 + d0 + dd];
                a0 += wgt[i] * ov.x; a1 += wgt[i] * ov.y;
                a2 += wgt[i] * ov.z; a3 += wgt[i] * ov.w;
            }
        }
        B4 p;
        p.v[0] = __float2bfloat16(a0 * invL);
        p.v[1] = __float2bfloat16(a1 * invL);
        p.v[2] = __float2bfloat16(a2 * invL);
        p.v[3] = __float2bfloat16(a3 * invL);
        *(B4*)&yrow[dd] = p;
    }
}

// ---------------------------------------------------------------- launch
extern "C" void kernel_launch(void* const* d_in, const int* in_sizes, int n_in,
                              void* d_out, int out_size, void* d_ws, size_t ws_size,
                              hipStream_t stream) {
    const float* x    = (const float*)d_in[0];
    const float* wqkv = (const float*)d_in[1];
    const float* wout = (const float*)d_in[2];
    float* out = (float*)d_out;

    char* ws = (char*)d_ws;
    bf16*  xb    = (bf16*)(ws);                         //  8,388,608
    bf16*  wqkvb = (bf16*)(ws + 8388608);               // 25,165,824
    bf16*  woutb = (bf16*)(ws + 33554432);               //  8,388,608
    float* qkvf  = (float*)(ws + 41943040);             // 50,331,648 (reused as `part` after vtrans)
    bf16*  qb    = (bf16*)(ws + 92274688);              //  8,388,608
    bf16*  kb    = (bf16*)(ws + 100663296);             //  8,388,608
    bf16*  vt    = (bf16*)(ws + 109051904);             //  8,388,608  [h][d][t]
    bf16*  yb    = (bf16*)(ws + 117440512);             //  8,388,608

    cast_all_k<<<10240, 256, 0, stream>>>(x, wqkv, wout, xb, wqkvb, woutb);
    gemm_bt<<<dim3(48, 16), 256, 0, stream>>>(xb, wqkvb, qkvf, 2048, 6144, 2048);
    normrope_k<<<dim3(2048, 16), 128, 0, stream>>>(qkvf, qb, kb);
    vtrans_k<<<dim3(32, 2, 16), 256, 0, stream>>>(qkvf, vt);
    attn_main_k<<<dim3(4, 32, 16), 256, 0, stream>>>(qb, kb, vt, qkvf);
    attn_merge_k<<<dim3(32, 16), 256, 0, stream>>>(qkvf, yb);
    gemm_bt<<<dim3(16, 16), 256, 0, stream>>>(yb, woutb, out, 2048, 2048, 2048);
}

// Round 4
// 371.794 us; speedup vs baseline: 1.0443x; 1.0443x over previous
//
#include <hip/hip_runtime.h>
#include <hip/hip_bf16.h>
#include <stdint.h>

typedef __hip_bfloat16 bf16;
typedef __bf16 bf16x8 __attribute__((ext_vector_type(8)));
typedef float f32x4 __attribute__((ext_vector_type(4)));

#define MFMA16(a, b, c) __builtin_amdgcn_mfma_f32_16x16x32_bf16((a), (b), (c), 0, 0, 0)

__device__ __forceinline__ void gload_lds16(const void* g, void* l) {
    __builtin_amdgcn_global_load_lds((const __attribute__((address_space(1))) void*)g,
                                     (__attribute__((address_space(3))) void*)l, 16, 0, 0);
}

// ---------------------------------------------------------------- cast kernel
struct alignas(16) B8 { bf16 v[8]; };
struct alignas(8)  B4 { bf16 v[4]; };

__global__ __launch_bounds__(256) void cast_all_k(
    const float* __restrict__ x, const float* __restrict__ wqkv, const float* __restrict__ wout,
    bf16* __restrict__ xb, bf16* __restrict__ wqkvb, bf16* __restrict__ woutb) {
    const size_t NX = (size_t)2048 * 2048 / 8;
    const size_t NW = (size_t)3 * 2048 * 2048 / 8;
    size_t i = (size_t)blockIdx.x * 256 + threadIdx.x;
    const float* s; bf16* d;
    if (i < NX)            { s = x;    d = xb; }
    else if (i < NX + NW)  { s = wqkv; d = wqkvb; i -= NX; }
    else                   { s = wout; d = woutb; i -= NX + NW; }
    float4 a = ((const float4*)s)[2 * i];
    float4 b = ((const float4*)s)[2 * i + 1];
    B8 t;
    t.v[0] = __float2bfloat16(a.x); t.v[1] = __float2bfloat16(a.y);
    t.v[2] = __float2bfloat16(a.z); t.v[3] = __float2bfloat16(a.w);
    t.v[4] = __float2bfloat16(b.x); t.v[5] = __float2bfloat16(b.y);
    t.v[6] = __float2bfloat16(b.z); t.v[7] = __float2bfloat16(b.w);
    ((B8*)d)[i] = t;
}

// ---------------------------------------------------------------- GEMM (B^T)
// 2-phase pipelined: dbuf LDS, counted vmcnt, raw barriers.
__global__ __launch_bounds__(256) void gemm_bt(
    const bf16* __restrict__ A, const bf16* __restrict__ B, float* __restrict__ C,
    int M, int N, int K) {
    __shared__ __align__(16) bf16 As[2][128 * 32];
    __shared__ __align__(16) bf16 Bs[2][128 * 32];
    const int t = threadIdx.x;
    const int lane = t & 63, w = t >> 6;
    const int wr = w >> 1, wc = w & 1;
    const int l15 = lane & 15, lg = lane >> 4;
    const int m0 = blockIdx.y * 128, n0 = blockIdx.x * 128;

    const int row = t >> 2, cb = t & 3;         // staging coords (c=0)
    const int row1 = (t + 256) >> 2, cb1 = t & 3;

    f32x4 acc[4][4] = {};

#define G_STAGE(buf, k0)                                                        \
    do {                                                                        \
        gload_lds16(&A[(size_t)(m0 + row) * K + (k0) + cb * 8],                 \
                    &As[buf][t * 8]);                                           \
        gload_lds16(&B[(size_t)(n0 + row) * K + (k0) + cb * 8],                 \
                    &Bs[buf][t * 8]);                                           \
        gload_lds16(&A[(size_t)(m0 + row1) * K + (k0) + cb1 * 8],               \
                    &As[buf][(t + 256) * 8]);                                   \
        gload_lds16(&B[(size_t)(n0 + row1) * K + (k0) + cb1 * 8],               \
                    &Bs[buf][(t + 256) * 8]);                                   \
    } while (0)

    G_STAGE(0, 0);
    int cur = 0;
    for (int k0 = 0; k0 < K; k0 += 32) {
        const bool hn = (k0 + 32 < K);
        if (hn) {
            G_STAGE(cur ^ 1, k0 + 32);
            asm volatile("s_waitcnt vmcnt(4)" ::: "memory");
        } else {
            asm volatile("s_waitcnt vmcnt(0)" ::: "memory");
        }
        __builtin_amdgcn_s_barrier();
        __builtin_amdgcn_sched_barrier(0);

        bf16x8 af[4], bfr[4];
#pragma unroll
        for (int mi = 0; mi < 4; ++mi)
            af[mi] = *(const bf16x8*)&As[cur][(wr * 64 + mi * 16 + l15) * 32 + lg * 8];
#pragma unroll
        for (int ni = 0; ni < 4; ++ni)
            bfr[ni] = *(const bf16x8*)&Bs[cur][(wc * 64 + ni * 16 + l15) * 32 + lg * 8];
#pragma unroll
        for (int mi = 0; mi < 4; ++mi)
#pragma unroll
            for (int ni = 0; ni < 4; ++ni)
                acc[mi][ni] = MFMA16(af[mi], bfr[ni], acc[mi][ni]);
        __builtin_amdgcn_s_barrier();
        cur ^= 1;
    }
#undef G_STAGE

#pragma unroll
    for (int mi = 0; mi < 4; ++mi) {
        int r0 = m0 + wr * 64 + mi * 16 + lg * 4;
#pragma unroll
        for (int ni = 0; ni < 4; ++ni) {
            int c0 = n0 + wc * 64 + ni * 16 + l15;
#pragma unroll
            for (int j = 0; j < 4; ++j)
                C[(size_t)(r0 + j) * N + c0] = acc[mi][ni][j];
        }
    }
}

// ---------------------------------------------------------------- RMSNorm+RoPE
__global__ __launch_bounds__(128) void normrope_k(
    const float* __restrict__ qkv, bf16* __restrict__ qb, bf16* __restrict__ kb) {
    const int t = blockIdx.x, h = blockIdx.y, d = threadIdx.x;
    const float* base = qkv + (size_t)t * 6144;
    float q = base[h * 128 + d];
    float k = base[2048 + h * 128 + d];

    __shared__ float red[4];
    __shared__ float qn[128], kn[128];
    float sq = q * q, sk = k * k;
#pragma unroll
    for (int m = 1; m <= 32; m <<= 1) {
        sq += __shfl_xor(sq, m);
        sk += __shfl_xor(sk, m);
    }
    if ((d & 63) == 0) { red[(d >> 6) * 2] = sq; red[(d >> 6) * 2 + 1] = sk; }
    __syncthreads();
    float rq = rsqrtf((red[0] + red[2]) * (1.0f / 128.0f) + 1e-6f);
    float rk = rsqrtf((red[1] + red[3]) * (1.0f / 128.0f) + 1e-6f);
    qn[d] = q * rq;
    kn[d] = k * rk;
    __syncthreads();

    int j = d & 63;
    float c = 1.0f, s = 0.0f;
    if (j < 32) {
        float af = exp2f(-10.0f * (float)j / 31.0f);
        float theta = (float)t * af;
        sincosf(theta, &s, &c);
    }
    float oq, ok;
    if (d < 64) { oq =  qn[d] * c + qn[d + 64] * s;  ok =  kn[d] * c + kn[d + 64] * s; }
    else        { oq = -qn[d - 64] * s + qn[d] * c;  ok = -kn[d - 64] * s + kn[d] * c; }

    size_t oidx = ((size_t)h * 2048 + t) * 128 + d;
    qb[oidx] = __float2bfloat16(oq * 0.08838834764831845f);
    kb[oidx] = __float2bfloat16(ok);
}

// ---------------------------------------------------------------- V transpose
__global__ __launch_bounds__(256) void vtrans_k(
    const float* __restrict__ qkv, bf16* __restrict__ vt) {
    __shared__ bf16 Ts[64][72];
    const int t0 = blockIdx.x * 64, d0 = blockIdx.y * 64, h = blockIdx.z;
    const int tid = threadIdx.x;
#pragma unroll
    for (int it = 0; it < 4; ++it) {
        int f = tid + it * 256;
        int tl = f >> 4, dl = (f & 15) * 4;
        float4 v = *(const float4*)&qkv[(size_t)(t0 + tl) * 6144 + 4096 + h * 128 + d0 + dl];
        Ts[tl][dl + 0] = __float2bfloat16(v.x);
        Ts[tl][dl + 1] = __float2bfloat16(v.y);
        Ts[tl][dl + 2] = __float2bfloat16(v.z);
        Ts[tl][dl + 3] = __float2bfloat16(v.w);
    }
    __syncthreads();
#pragma unroll
    for (int it = 0; it < 2; ++it) {
        int f = tid + it * 256;
        int dl = f >> 3, tc = f & 7;
        B8 p;
#pragma unroll
        for (int i = 0; i < 8; ++i) p.v[i] = Ts[tc * 8 + i][dl];
        *(B8*)&vt[((size_t)h * 128 + d0 + dl) * 2048 + t0 + tc * 8] = p;
    }
}

// ---------------------------------------------------------------- attention (split-KV, 2-phase pipelined)
__global__ __launch_bounds__(256) void attn_main_k(
    const bf16* __restrict__ qg, const bf16* __restrict__ kg,
    const bf16* __restrict__ vt, float* __restrict__ part) {
    const int T = 2048, D = 128;
    const int cz = blockIdx.x, qt = blockIdx.y, h = blockIdx.z;
    if (cz > (qt >> 3)) return;
    const int qb0 = qt * 64;
    const int kstart = cz * 512;
    const int kend = min(kstart + 512, (qt + 1) * 64);

    __shared__ __align__(16) bf16 Ks[2][64 * 128];  // [key][d], 16B-chunk XOR swizzle
    __shared__ __align__(16) bf16 Vs[2][64 * 128];  // [d][key], 16B-chunk XOR swizzle
    __shared__ __align__(16) bf16 Ps[4][16 * 64];   // per-wave P, swizzled

    const int t = threadIdx.x;
    const int lane = t & 63, w = t >> 6;
    const int l15 = lane & 15, lg = lane >> 4;

    const size_t qoff = ((size_t)h * T + qb0 + w * 16 + l15) * D;
    bf16x8 qf[4];
#pragma unroll
    for (int ks = 0; ks < 4; ++ks)
        qf[ks] = *(const bf16x8*)&qg[qoff + ks * 32 + lg * 8];

    f32x4 o[8] = {};
    float mrow[4] = {-1e30f, -1e30f, -1e30f, -1e30f};
    float lrow[4] = {0.f, 0.f, 0.f, 0.f};

    // staging coords (per c-iteration f = t + c*256)
#define A_STAGE(buf, k0)                                                         \
    do {                                                                         \
        _Pragma("unroll")                                                        \
        for (int c = 0; c < 4; ++c) {                                            \
            int f = t + c * 256;                                                 \
            int krow = f >> 4, kc = f & 15;                                      \
            gload_lds16(&kg[((size_t)h * T + (k0) + krow) * D + ((kc ^ (krow & 15)) * 8)], \
                        &Ks[buf][f * 8]);                                        \
            int dr = f >> 3, vc = f & 7;                                         \
            gload_lds16(&vt[((size_t)h * D + dr) * T + (k0) + ((vc ^ (dr & 7)) * 8)],      \
                        &Vs[buf][f * 8]);                                        \
        }                                                                        \
    } while (0)

    A_STAGE(0, kstart);
    int cur = 0;
    for (int k0 = kstart; k0 < kend; k0 += 64) {
        const bool hn = (k0 + 64 < kend);
        if (hn) {
            A_STAGE(cur ^ 1, k0 + 64);
            asm volatile("s_waitcnt vmcnt(8)" ::: "memory");
        } else {
            asm volatile("s_waitcnt vmcnt(0)" ::: "memory");
        }
        __builtin_amdgcn_s_barrier();
        __builtin_amdgcn_sched_barrier(0);

        // --- S = Q K^T
        f32x4 sc[4] = {};
#pragma unroll
        for (int ks = 0; ks < 4; ++ks) {
#pragma unroll
            for (int nb = 0; nb < 4; ++nb) {
                int key = nb * 16 + l15;
                int c = ks * 4 + lg;
                bf16x8 kf = *(const bf16x8*)&Ks[cur][key * 128 + ((c ^ (key & 15)) * 8)];
                sc[nb] = MFMA16(qf[ks], kf, sc[nb]);
            }
        }

        const bool diag = (k0 == qb0);
        const int qrow_base = qb0 + w * 16 + lg * 4;
#pragma unroll
        for (int j = 0; j < 4; ++j) {
            float s0 = sc[0][j], s1 = sc[1][j], s2 = sc[2][j], s3 = sc[3][j];
            if (diag) {
                int qrow = qrow_base + j;
                if (k0 + l15 > qrow)      s0 = -1e30f;
                if (k0 + 16 + l15 > qrow) s1 = -1e30f;
                if (k0 + 32 + l15 > qrow) s2 = -1e30f;
                if (k0 + 48 + l15 > qrow) s3 = -1e30f;
            }
            float tm = fmaxf(fmaxf(s0, s1), fmaxf(s2, s3));
            tm = fmaxf(tm, __shfl_xor(tm, 1));
            tm = fmaxf(tm, __shfl_xor(tm, 2));
            tm = fmaxf(tm, __shfl_xor(tm, 4));
            tm = fmaxf(tm, __shfl_xor(tm, 8));
            float mnew = fmaxf(mrow[j], tm);
            float fac = __expf(mrow[j] - mnew);
            float p0 = __expf(s0 - mnew), p1 = __expf(s1 - mnew);
            float p2 = __expf(s2 - mnew), p3 = __expf(s3 - mnew);
            float ps = (p0 + p1) + (p2 + p3);
            ps += __shfl_xor(ps, 1);
            ps += __shfl_xor(ps, 2);
            ps += __shfl_xor(ps, 4);
            ps += __shfl_xor(ps, 8);
            lrow[j] = lrow[j] * fac + ps;
            mrow[j] = mnew;
#pragma unroll
            for (int nd = 0; nd < 8; ++nd) o[nd][j] *= fac;
            int prow = lg * 4 + j;
            int sub = l15 & 7, hi = l15 >> 3;
            bf16* pw = &Ps[w][prow * 64 + sub];
            pw[(((0 + hi) ^ (prow & 7)) * 8)] = __float2bfloat16(p0);
            pw[(((2 + hi) ^ (prow & 7)) * 8)] = __float2bfloat16(p1);
            pw[(((4 + hi) ^ (prow & 7)) * 8)] = __float2bfloat16(p2);
            pw[(((6 + hi) ^ (prow & 7)) * 8)] = __float2bfloat16(p3);
        }

        // --- O += P V
#pragma unroll
        for (int hk = 0; hk < 2; ++hk) {
            bf16x8 pf = *(const bf16x8*)&Ps[w][l15 * 64 + (((hk * 4 + lg) ^ (l15 & 7)) * 8)];
#pragma unroll
            for (int nd = 0; nd < 8; ++nd) {
                int dd = nd * 16 + l15;
                bf16x8 vf = *(const bf16x8*)&Vs[cur][dd * 64 + (((hk * 4 + lg) ^ (dd & 7)) * 8)];
                o[nd] = MFMA16(pf, vf, o[nd]);
            }
        }
        __builtin_amdgcn_s_barrier();
        cur ^= 1;
    }
#undef A_STAGE

    // --- write partial record
    int b = qt >> 3, rr = qt & 7;
    int slot = h * 80 + qt + 4 * b * (b - 1) + rr * b + cz;
    float* rec = part + (size_t)slot * 8320;
    if (l15 == 0) {
#pragma unroll
        for (int j = 0; j < 4; ++j) {
            rec[w * 16 + lg * 4 + j] = mrow[j];
            rec[64 + w * 16 + lg * 4 + j] = lrow[j];
        }
    }
#pragma unroll
    for (int nd = 0; nd < 8; ++nd)
#pragma unroll
        for (int j = 0; j < 4; ++j)
            rec[128 + (w * 16 + lg * 4 + j) * 128 + nd * 16 + l15] = o[nd][j];
}

// ---------------------------------------------------------------- merge
__global__ __launch_bounds__(256) void attn_merge_k(
    const float* __restrict__ part, bf16* __restrict__ y) {
    const int qt = blockIdx.x, h = blockIdx.y, tid = threadIdx.x;
    const int nch = (qt >> 3) + 1;
    int b = qt >> 3, rr = qt & 7;
    const int base = h * 80 + qt + 4 * b * (b - 1) + rr * b;
    const int r = tid >> 2;
    const int d0 = (tid & 3) * 32;

    float mi[4], li[4], wgt[4];
    float M = -1e30f;
#pragma unroll
    for (int i = 0; i < 4; ++i) {
        if (i < nch) {
            mi[i] = part[(size_t)(base + i) * 8320 + r];
            li[i] = part[(size_t)(base + i) * 8320 + 64 + r];
            M = fmaxf(M, mi[i]);
        } else { mi[i] = -1e30f; li[i] = 0.f; }
    }
    float L = 0.f;
#pragma unroll
    for (int i = 0; i < 4; ++i) {
        wgt[i] = (i < nch) ? __expf(mi[i] - M) : 0.f;
        L += li[i] * wgt[i];
    }
    float invL = 1.0f / L;

    bf16* yrow = &y[(size_t)(qt * 64 + r) * 2048 + h * 128 + d0];
#pragma unroll
    for (int dd = 0; dd < 32; dd += 4) {
        float a0 = 0.f, a1 = 0.f, a2 = 0.f, a3 = 0.f;
#pragma unroll
        for (int i = 0; i < 4; ++i) {
            if (i < nch) {
                const float4 ov = *(const float4*)&part[(size_t)(base + i) * 8320 + 128 + r * 128 + d0 + dd];
                a0 += wgt[i] * ov.x; a1 += wgt[i] * ov.y;
                a2 += wgt[i] * ov.z; a3 += wgt[i] * ov.w;
            }
        }
        B4 p;
        p.v[0] = __float2bfloat16(a0 * invL);
        p.v[1] = __float2bfloat16(a1 * invL);
        p.v[2] = __float2bfloat16(a2 * invL);
        p.v[3] = __float2bfloat16(a3 * invL);
        *(B4*)&yrow[dd] = p;
    }
}

// ---------------------------------------------------------------- launch
extern "C" void kernel_launch(void* const* d_in, const int* in_sizes, int n_in,
                              void* d_out, int out_size, void* d_ws, size_t ws_size,
                              hipStream_t stream) {
    const float* x    = (const float*)d_in[0];
    const float* wqkv = (const float*)d_in[1];
    const float* wout = (const float*)d_in[2];
    float* out = (float*)d_out;

    char* ws = (char*)d_ws;
    bf16*  xb    = (bf16*)(ws);                         //  8,388,608
    bf16*  wqkvb = (bf16*)(ws + 8388608);               // 25,165,824
    bf16*  woutb = (bf16*)(ws + 33554432);              //  8,388,608
    float* qkvf  = (float*)(ws + 41943040);             // 50,331,648 (reused as `part`)
    bf16*  qb    = (bf16*)(ws + 92274688);              //  8,388,608
    bf16*  kb    = (bf16*)(ws + 100663296);             //  8,388,608
    bf16*  vt    = (bf16*)(ws + 109051904);             //  8,388,608  [h][d][t]
    bf16*  yb    = (bf16*)(ws + 117440512);             //  8,388,608

    cast_all_k<<<10240, 256, 0, stream>>>(x, wqkv, wout, xb, wqkvb, woutb);
    gemm_bt<<<dim3(48, 16), 256, 0, stream>>>(xb, wqkvb, qkvf, 2048, 6144, 2048);
    normrope_k<<<dim3(2048, 16), 128, 0, stream>>>(qkvf, qb, kb);
    vtrans_k<<<dim3(32, 2, 16), 256, 0, stream>>>(qkvf, vt);
    attn_main_k<<<dim3(4, 32, 16), 256, 0, stream>>>(qb, kb, vt, qkvf);
    attn_merge_k<<<dim3(32, 16), 256, 0, stream>>>(qkvf, yb);
    gemm_bt<<<dim3(16, 16), 256, 0, stream>>>(yb, woutb, out, 2048, 2048, 2048);
}

// Round 5
// 355.721 us; speedup vs baseline: 1.0915x; 1.0452x over previous
//
#include <hip/hip_runtime.h>
#include <hip/hip_bf16.h>
#include <stdint.h>

typedef __hip_bfloat16 bf16;
typedef __bf16 bf16x8 __attribute__((ext_vector_type(8)));
typedef float f32x4 __attribute__((ext_vector_type(4)));

#define MFMA16(a, b, c) __builtin_amdgcn_mfma_f32_16x16x32_bf16((a), (b), (c), 0, 0, 0)

__device__ __forceinline__ void gload_lds16(const void* g, void* l) {
    __builtin_amdgcn_global_load_lds((const __attribute__((address_space(1))) void*)g,
                                     (__attribute__((address_space(3))) void*)l, 16, 0, 0);
}

// ---------------------------------------------------------------- cast kernel
struct alignas(16) B8 { bf16 v[8]; };
struct alignas(8)  B4 { bf16 v[4]; };

__global__ __launch_bounds__(256) void cast_all_k(
    const float* __restrict__ x, const float* __restrict__ wqkv, const float* __restrict__ wout,
    bf16* __restrict__ xb, bf16* __restrict__ wqkvb, bf16* __restrict__ woutb) {
    const size_t NX = (size_t)2048 * 2048 / 8;
    const size_t NW = (size_t)3 * 2048 * 2048 / 8;
    size_t i = (size_t)blockIdx.x * 256 + threadIdx.x;
    const float* s; bf16* d;
    if (i < NX)            { s = x;    d = xb; }
    else if (i < NX + NW)  { s = wqkv; d = wqkvb; i -= NX; }
    else                   { s = wout; d = woutb; i -= NX + NW; }
    float4 a = ((const float4*)s)[2 * i];
    float4 b = ((const float4*)s)[2 * i + 1];
    B8 t;
    t.v[0] = __float2bfloat16(a.x); t.v[1] = __float2bfloat16(a.y);
    t.v[2] = __float2bfloat16(a.z); t.v[3] = __float2bfloat16(a.w);
    t.v[4] = __float2bfloat16(b.x); t.v[5] = __float2bfloat16(b.y);
    t.v[6] = __float2bfloat16(b.z); t.v[7] = __float2bfloat16(b.w);
    ((B8*)d)[i] = t;
}

// ---------------------------------------------------------------- GEMM (B^T)
// 2-phase pipelined: dbuf LDS, counted vmcnt, raw barriers. (round-4 version)
__global__ __launch_bounds__(256) void gemm_bt(
    const bf16* __restrict__ A, const bf16* __restrict__ B, float* __restrict__ C,
    int M, int N, int K) {
    __shared__ __align__(16) bf16 As[2][128 * 32];
    __shared__ __align__(16) bf16 Bs[2][128 * 32];
    const int t = threadIdx.x;
    const int lane = t & 63, w = t >> 6;
    const int wr = w >> 1, wc = w & 1;
    const int l15 = lane & 15, lg = lane >> 4;
    const int m0 = blockIdx.y * 128, n0 = blockIdx.x * 128;

    const int row = t >> 2, cb = t & 3;
    const int row1 = (t + 256) >> 2, cb1 = t & 3;

    f32x4 acc[4][4] = {};

#define G_STAGE(buf, k0)                                                        \
    do {                                                                        \
        gload_lds16(&A[(size_t)(m0 + row) * K + (k0) + cb * 8],                 \
                    &As[buf][t * 8]);                                           \
        gload_lds16(&B[(size_t)(n0 + row) * K + (k0) + cb * 8],                 \
                    &Bs[buf][t * 8]);                                           \
        gload_lds16(&A[(size_t)(m0 + row1) * K + (k0) + cb1 * 8],               \
                    &As[buf][(t + 256) * 8]);                                   \
        gload_lds16(&B[(size_t)(n0 + row1) * K + (k0) + cb1 * 8],               \
                    &Bs[buf][(t + 256) * 8]);                                   \
    } while (0)

    G_STAGE(0, 0);
    int cur = 0;
    for (int k0 = 0; k0 < K; k0 += 32) {
        const bool hn = (k0 + 32 < K);
        if (hn) {
            G_STAGE(cur ^ 1, k0 + 32);
            asm volatile("s_waitcnt vmcnt(4)" ::: "memory");
        } else {
            asm volatile("s_waitcnt vmcnt(0)" ::: "memory");
        }
        __builtin_amdgcn_s_barrier();
        __builtin_amdgcn_sched_barrier(0);

        bf16x8 af[4], bfr[4];
#pragma unroll
        for (int mi = 0; mi < 4; ++mi)
            af[mi] = *(const bf16x8*)&As[cur][(wr * 64 + mi * 16 + l15) * 32 + lg * 8];
#pragma unroll
        for (int ni = 0; ni < 4; ++ni)
            bfr[ni] = *(const bf16x8*)&Bs[cur][(wc * 64 + ni * 16 + l15) * 32 + lg * 8];
#pragma unroll
        for (int mi = 0; mi < 4; ++mi)
#pragma unroll
            for (int ni = 0; ni < 4; ++ni)
                acc[mi][ni] = MFMA16(af[mi], bfr[ni], acc[mi][ni]);
        __builtin_amdgcn_s_barrier();
        cur ^= 1;
    }
#undef G_STAGE

#pragma unroll
    for (int mi = 0; mi < 4; ++mi) {
        int r0 = m0 + wr * 64 + mi * 16 + lg * 4;
#pragma unroll
        for (int ni = 0; ni < 4; ++ni) {
            int c0 = n0 + wc * 64 + ni * 16 + l15;
#pragma unroll
            for (int j = 0; j < 4; ++j)
                C[(size_t)(r0 + j) * N + c0] = acc[mi][ni][j];
        }
    }
}

// ---------------------------------------------------------------- RMSNorm+RoPE
__global__ __launch_bounds__(128) void normrope_k(
    const float* __restrict__ qkv, bf16* __restrict__ qb, bf16* __restrict__ kb) {
    const int t = blockIdx.x, h = blockIdx.y, d = threadIdx.x;
    const float* base = qkv + (size_t)t * 6144;
    float q = base[h * 128 + d];
    float k = base[2048 + h * 128 + d];

    __shared__ float red[4];
    __shared__ float qn[128], kn[128];
    float sq = q * q, sk = k * k;
#pragma unroll
    for (int m = 1; m <= 32; m <<= 1) {
        sq += __shfl_xor(sq, m);
        sk += __shfl_xor(sk, m);
    }
    if ((d & 63) == 0) { red[(d >> 6) * 2] = sq; red[(d >> 6) * 2 + 1] = sk; }
    __syncthreads();
    float rq = rsqrtf((red[0] + red[2]) * (1.0f / 128.0f) + 1e-6f);
    float rk = rsqrtf((red[1] + red[3]) * (1.0f / 128.0f) + 1e-6f);
    qn[d] = q * rq;
    kn[d] = k * rk;
    __syncthreads();

    int j = d & 63;
    float c = 1.0f, s = 0.0f;
    if (j < 32) {
        float af = exp2f(-10.0f * (float)j / 31.0f);
        float theta = (float)t * af;
        sincosf(theta, &s, &c);
    }
    float oq, ok;
    if (d < 64) { oq =  qn[d] * c + qn[d + 64] * s;  ok =  kn[d] * c + kn[d + 64] * s; }
    else        { oq = -qn[d - 64] * s + qn[d] * c;  ok = -kn[d - 64] * s + kn[d] * c; }

    size_t oidx = ((size_t)h * 2048 + t) * 128 + d;
    qb[oidx] = __float2bfloat16(oq * 0.08838834764831845f);
    kb[oidx] = __float2bfloat16(ok);
}

// ---------------------------------------------------------------- V transpose
__global__ __launch_bounds__(256) void vtrans_k(
    const float* __restrict__ qkv, bf16* __restrict__ vt) {
    __shared__ bf16 Ts[64][72];
    const int t0 = blockIdx.x * 64, d0 = blockIdx.y * 64, h = blockIdx.z;
    const int tid = threadIdx.x;
#pragma unroll
    for (int it = 0; it < 4; ++it) {
        int f = tid + it * 256;
        int tl = f >> 4, dl = (f & 15) * 4;
        float4 v = *(const float4*)&qkv[(size_t)(t0 + tl) * 6144 + 4096 + h * 128 + d0 + dl];
        Ts[tl][dl + 0] = __float2bfloat16(v.x);
        Ts[tl][dl + 1] = __float2bfloat16(v.y);
        Ts[tl][dl + 2] = __float2bfloat16(v.z);
        Ts[tl][dl + 3] = __float2bfloat16(v.w);
    }
    __syncthreads();
#pragma unroll
    for (int it = 0; it < 2; ++it) {
        int f = tid + it * 256;
        int dl = f >> 3, tc = f & 7;
        B8 p;
#pragma unroll
        for (int i = 0; i < 8; ++i) p.v[i] = Ts[tc * 8 + i][dl];
        *(B8*)&vt[((size_t)h * 128 + d0 + dl) * 2048 + t0 + tc * 8] = p;
    }
}

// ---------------------------------------------------------------- attention (split-KV, chunk=256 keys)
// Grid (cz=8, qt=32, h=16). Active if cz <= qt>>2. Block = 4 waves, QBLK=64.
// Per chunk <=4 KV tiles of 64. Records: m[64]f32 | l[64]f32 | O[64][128]bf16 (16896 B).
__global__ __launch_bounds__(256) void attn_main_k(
    const bf16* __restrict__ qg, const bf16* __restrict__ kg,
    const bf16* __restrict__ vt, char* __restrict__ part) {
    const int T = 2048, D = 128;
    const int cz = blockIdx.x, qt = blockIdx.y, h = blockIdx.z;
    if (cz > (qt >> 2)) return;
    const int qb0 = qt * 64;
    const int kstart = cz * 256;
    const int kend = min(kstart + 256, (qt + 1) * 64);

    __shared__ __align__(16) bf16 Ks[64 * 128];   // [key][d], 16B-chunk XOR swizzle
    __shared__ __align__(16) bf16 Vs[128 * 64];   // [d][key], 16B-chunk XOR swizzle
    __shared__ __align__(16) bf16 Ps[4][16 * 64]; // per-wave P, swizzled

    const int t = threadIdx.x;
    const int lane = t & 63, w = t >> 6;
    const int l15 = lane & 15, lg = lane >> 4;

    const size_t qoff = ((size_t)h * T + qb0 + w * 16 + l15) * D;
    bf16x8 qf[4];
#pragma unroll
    for (int ks = 0; ks < 4; ++ks)
        qf[ks] = *(const bf16x8*)&qg[qoff + ks * 32 + lg * 8];

    bf16x8 onesf;
#pragma unroll
    for (int i = 0; i < 8; ++i) onesf[i] = (__bf16)1.0f;

    f32x4 o[8] = {};
    float mrow[4] = {-1e30f, -1e30f, -1e30f, -1e30f};
    float lrow[4] = {0.f, 0.f, 0.f, 0.f};

    for (int k0 = kstart; k0 < kend; k0 += 64) {
        // --- stage K [64 keys][128 d] and V^T [128 d][64 keys]
#pragma unroll
        for (int c = 0; c < 4; ++c) {
            int f = t + c * 256;
            int krow = f >> 4, kc = f & 15;
            gload_lds16(&kg[((size_t)h * T + k0 + krow) * D + ((kc ^ (krow & 15)) * 8)],
                        &Ks[f * 8]);
            int dr = f >> 3, vc = f & 7;
            gload_lds16(&vt[((size_t)h * D + dr) * T + k0 + ((vc ^ (dr & 7)) * 8)],
                        &Vs[f * 8]);
        }
        __syncthreads();

        // --- S = Q K^T (scale folded into Q)
        f32x4 sc[4] = {};
#pragma unroll
        for (int ks = 0; ks < 4; ++ks) {
#pragma unroll
            for (int nb = 0; nb < 4; ++nb) {
                int key = nb * 16 + l15;
                int c = ks * 4 + lg;
                bf16x8 kf = *(const bf16x8*)&Ks[key * 128 + ((c ^ (key & 15)) * 8)];
                sc[nb] = MFMA16(qf[ks], kf, sc[nb]);
            }
        }

        const bool diag = (k0 == qb0);
        const int qrow_base = qb0 + w * 16 + lg * 4;
        float fac[4];
        bool anyresc = false;
#pragma unroll
        for (int j = 0; j < 4; ++j) {
            float s0 = sc[0][j], s1 = sc[1][j], s2 = sc[2][j], s3 = sc[3][j];
            if (diag) {
                int qrow = qrow_base + j;
                if (k0 + l15 > qrow)      s0 = -1e30f;
                if (k0 + 16 + l15 > qrow) s1 = -1e30f;
                if (k0 + 32 + l15 > qrow) s2 = -1e30f;
                if (k0 + 48 + l15 > qrow) s3 = -1e30f;
            }
            float tm = fmaxf(fmaxf(s0, s1), fmaxf(s2, s3));
            tm = fmaxf(tm, __shfl_xor(tm, 1));
            tm = fmaxf(tm, __shfl_xor(tm, 2));
            tm = fmaxf(tm, __shfl_xor(tm, 4));
            tm = fmaxf(tm, __shfl_xor(tm, 8));
            // defer-max (T13): skip rescale when row maxes grew by <= 6
            if (__all(tm <= mrow[j] + 6.0f)) {
                fac[j] = 1.0f;                // keep stale max; P bounded by e^6
            } else {
                float mnew = fmaxf(mrow[j], tm);
                fac[j] = __expf(mrow[j] - mnew);
                mrow[j] = mnew;
                anyresc = true;
            }
            float p0 = __expf(s0 - mrow[j]), p1 = __expf(s1 - mrow[j]);
            float p2 = __expf(s2 - mrow[j]), p3 = __expf(s3 - mrow[j]);
            int prow = lg * 4 + j;
            int sub = l15 & 7, hi = l15 >> 3;
            bf16* pw = &Ps[w][prow * 64 + sub];
            pw[(((0 + hi) ^ (prow & 7)) * 8)] = __float2bfloat16(p0);
            pw[(((2 + hi) ^ (prow & 7)) * 8)] = __float2bfloat16(p1);
            pw[(((4 + hi) ^ (prow & 7)) * 8)] = __float2bfloat16(p2);
            pw[(((6 + hi) ^ (prow & 7)) * 8)] = __float2bfloat16(p3);
        }

        if (anyresc) {
#pragma unroll
            for (int nd = 0; nd < 8; ++nd)
#pragma unroll
                for (int j = 0; j < 4; ++j) o[nd][j] *= fac[j];
        }

        // --- O += P V ; l-sum via ones-operand MFMA (replaces shuffle-sum)
        f32x4 lsum = {};
#pragma unroll
        for (int hk = 0; hk < 2; ++hk) {
            bf16x8 pf = *(const bf16x8*)&Ps[w][l15 * 64 + (((hk * 4 + lg) ^ (l15 & 7)) * 8)];
            lsum = MFMA16(pf, onesf, lsum);
#pragma unroll
            for (int nd = 0; nd < 8; ++nd) {
                int dd = nd * 16 + l15;
                bf16x8 vf = *(const bf16x8*)&Vs[dd * 64 + (((hk * 4 + lg) ^ (dd & 7)) * 8)];
                o[nd] = MFMA16(pf, vf, o[nd]);
            }
        }
#pragma unroll
        for (int j = 0; j < 4; ++j) lrow[j] = lrow[j] * fac[j] + lsum[j];
        __syncthreads();
    }

    // --- write partial record (m,l fp32; O bf16)
    int B = qt >> 2, r4 = qt & 3;
    int slot = h * 144 + qt + 2 * B * (B - 1) + r4 * B + cz;
    char* rec = part + (size_t)slot * 16896;
    float* mrec = (float*)rec;
    float* lrec = (float*)(rec + 256);
    bf16*  orec = (bf16*)(rec + 512);
    if (l15 == 0) {
#pragma unroll
        for (int j = 0; j < 4; ++j) {
            mrec[w * 16 + lg * 4 + j] = mrow[j];
            lrec[w * 16 + lg * 4 + j] = lrow[j];
        }
    }
#pragma unroll
    for (int nd = 0; nd < 8; ++nd)
#pragma unroll
        for (int j = 0; j < 4; ++j)
            orec[(w * 16 + lg * 4 + j) * 128 + nd * 16 + l15] = __float2bfloat16(o[nd][j]);
}

// ---------------------------------------------------------------- merge
// Grid (qt=32, h=16), 256 thr: row r = tid>>2, d-range (tid&3)*32. <=8 partials.
__global__ __launch_bounds__(256) void attn_merge_k(
    const char* __restrict__ part, bf16* __restrict__ y) {
    const int qt = blockIdx.x, h = blockIdx.y, tid = threadIdx.x;
    const int nch = (qt >> 2) + 1;
    int B = qt >> 2, r4 = qt & 3;
    const int base = h * 144 + qt + 2 * B * (B - 1) + r4 * B;
    const int r = tid >> 2;
    const int d0 = (tid & 3) * 32;

    float mi[8], li[8], wgt[8];
    float M = -1e30f;
#pragma unroll
    for (int i = 0; i < 8; ++i) {
        if (i < nch) {
            const char* rec = part + (size_t)(base + i) * 16896;
            mi[i] = ((const float*)rec)[r];
            li[i] = ((const float*)(rec + 256))[r];
            M = fmaxf(M, mi[i]);
        } else { mi[i] = -1e30f; li[i] = 0.f; }
    }
    float L = 0.f;
#pragma unroll
    for (int i = 0; i < 8; ++i) {
        wgt[i] = (i < nch) ? __expf(mi[i] - M) : 0.f;
        L += li[i] * wgt[i];
    }
    float invL = 1.0f / L;

    bf16* yrow = &y[(size_t)(qt * 64 + r) * 2048 + h * 128 + d0];
#pragma unroll
    for (int dd = 0; dd < 32; dd += 8) {
        float facc[8] = {};
#pragma unroll
        for (int i = 0; i < 8; ++i) {
            if (i < nch) {
                const bf16* orec = (const bf16*)(part + (size_t)(base + i) * 16896 + 512);
                B8 ov = *(const B8*)&orec[r * 128 + d0 + dd];
#pragma unroll
                for (int e = 0; e < 8; ++e)
                    facc[e] += wgt[i] * __bfloat162float(ov.v[e]);
            }
        }
        B8 p;
#pragma unroll
        for (int e = 0; e < 8; ++e) p.v[e] = __float2bfloat16(facc[e] * invL);
        *(B8*)&yrow[dd] = p;
    }
}

// ---------------------------------------------------------------- launch
extern "C" void kernel_launch(void* const* d_in, const int* in_sizes, int n_in,
                              void* d_out, int out_size, void* d_ws, size_t ws_size,
                              hipStream_t stream) {
    const float* x    = (const float*)d_in[0];
    const float* wqkv = (const float*)d_in[1];
    const float* wout = (const float*)d_in[2];
    float* out = (float*)d_out;

    char* ws = (char*)d_ws;
    bf16*  xb    = (bf16*)(ws);                         //  8,388,608
    bf16*  wqkvb = (bf16*)(ws + 8388608);               // 25,165,824
    bf16*  woutb = (bf16*)(ws + 33554432);              //  8,388,608
    float* qkvf  = (float*)(ws + 41943040);             // 50,331,648 (reused as `part`: 2304*16896=38.9MB)
    bf16*  qb    = (bf16*)(ws + 92274688);              //  8,388,608
    bf16*  kb    = (bf16*)(ws + 100663296);             //  8,388,608
    bf16*  vt    = (bf16*)(ws + 109051904);             //  8,388,608  [h][d][t]
    bf16*  yb    = (bf16*)(ws + 117440512);             //  8,388,608

    cast_all_k<<<10240, 256, 0, stream>>>(x, wqkv, wout, xb, wqkvb, woutb);
    gemm_bt<<<dim3(48, 16), 256, 0, stream>>>(xb, wqkvb, qkvf, 2048, 6144, 2048);
    normrope_k<<<dim3(2048, 16), 128, 0, stream>>>(qkvf, qb, kb);
    vtrans_k<<<dim3(32, 2, 16), 256, 0, stream>>>(qkvf, vt);
    attn_main_k<<<dim3(8, 32, 16), 256, 0, stream>>>(qb, kb, vt, (char*)qkvf);
    attn_merge_k<<<dim3(32, 16), 256, 0, stream>>>((const char*)qkvf, yb);
    gemm_bt<<<dim3(16, 16), 256, 0, stream>>>(yb, woutb, out, 2048, 2048, 2048);
}